// Round 8
// baseline (760.797 us; speedup 1.0000x reference)
//
#include <hip/hip_runtime.h>
#include <hip/hip_bf16.h>
#include <hip/hip_fp16.h>

typedef _Float16 h2vec __attribute__((ext_vector_type(2)));
typedef _Float16 f16x8 __attribute__((ext_vector_type(8)));
typedef float f32x4 __attribute__((ext_vector_type(4)));

static __device__ __forceinline__ float fast_sigmoid(float x) {
  return __builtin_amdgcn_rcpf(1.f + __expf(-x));
}
static __device__ __forceinline__ float fast_tanh(float x) {
  return 1.f - 2.f * __builtin_amdgcn_rcpf(__expf(2.f * x) + 1.f);
}
static __device__ __forceinline__ float fdot2u(unsigned int a, unsigned int b, float c) {
#if __has_builtin(__builtin_amdgcn_fdot2)
  return __builtin_amdgcn_fdot2(__builtin_bit_cast(h2vec, a),
                                __builtin_bit_cast(h2vec, b), c, false);
#else
  h2vec av = __builtin_bit_cast(h2vec, a);
  h2vec bv = __builtin_bit_cast(h2vec, b);
  return c + (float)av[0] * (float)bv[0] + (float)av[1] * (float)bv[1];
#endif
}
template<int CTRL>
static __device__ __forceinline__ float dpp_add(float v) {
  int x = __builtin_bit_cast(int, v);
  int y = __builtin_amdgcn_update_dpp(0, x, CTRL, 0xF, 0xF, true);
  return v + __builtin_bit_cast(float, y);
}
template<int CTRL>
static __device__ __forceinline__ float dpp_mov(float v) {
  int x = __builtin_bit_cast(int, v);
  int y = __builtin_amdgcn_update_dpp(0, x, CTRL, 0xF, 0xF, true);
  return __builtin_bit_cast(float, y);
}

// ---------------------------------------------------------------------------
// f16-MFMA GEMM, fp32 out (head layers). C = act(A @ W^T + bias).
// MODE 1: relu(val + b0[n]); MODE 2: tanh(val + b0[n]).
// (Proven structure from round 6: 128x64 tile, XOR-swizzled LDS, 0 conflicts.)
// ---------------------------------------------------------------------------
template<int MODE>
__global__ __launch_bounds__(256) void gemm_mfma(
    const float* __restrict__ A, const float* __restrict__ W,
    const float* __restrict__ b0, const float* __restrict__ b1,
    float* __restrict__ C, int M, int N, int K) {
  __shared__ __align__(16) unsigned char As[128 * 128];
  __shared__ __align__(16) unsigned char Bs[64 * 128];
  const int tid = threadIdx.x;
  const int wave = tid >> 6, l = tid & 63;
  const int wm = wave >> 1, wn = wave & 1;
  const int m0 = blockIdx.x * 128, n0 = blockIdx.y * 64;
  const int lrow = l & 15, lq = l >> 4;

  f32x4 acc[4][2] = {};
  const int arow = tid >> 1, akc = (tid & 1) * 32;
  const int brow = tid >> 2, bkc = (tid & 3) * 16;

  for (int k0 = 0; k0 < K; k0 += 64) {
    {
      const float* src = A + (size_t)(m0 + arow) * K + k0 + akc;
#pragma unroll
      for (int u = 0; u < 4; ++u) {
        float4 v0 = *reinterpret_cast<const float4*>(src + u * 8);
        float4 v1 = *reinterpret_cast<const float4*>(src + u * 8 + 4);
        f16x8 h;
        h[0] = (_Float16)v0.x; h[1] = (_Float16)v0.y;
        h[2] = (_Float16)v0.z; h[3] = (_Float16)v0.w;
        h[4] = (_Float16)v1.x; h[5] = (_Float16)v1.y;
        h[6] = (_Float16)v1.z; h[7] = (_Float16)v1.w;
        const int kbyte = (akc + u * 8) * 2;
        *reinterpret_cast<f16x8*>(&As[arow * 128 + (kbyte ^ ((arow & 7) << 4))]) = h;
      }
    }
    {
      const float* src = W + (size_t)(n0 + brow) * K + k0 + bkc;
#pragma unroll
      for (int u = 0; u < 2; ++u) {
        float4 v0 = *reinterpret_cast<const float4*>(src + u * 8);
        float4 v1 = *reinterpret_cast<const float4*>(src + u * 8 + 4);
        f16x8 h;
        h[0] = (_Float16)v0.x; h[1] = (_Float16)v0.y;
        h[2] = (_Float16)v0.z; h[3] = (_Float16)v0.w;
        h[4] = (_Float16)v1.x; h[5] = (_Float16)v1.y;
        h[6] = (_Float16)v1.z; h[7] = (_Float16)v1.w;
        const int kbyte = (bkc + u * 8) * 2;
        *reinterpret_cast<f16x8*>(&Bs[brow * 128 + (kbyte ^ ((brow & 7) << 4))]) = h;
      }
    }
    __syncthreads();
#pragma unroll
    for (int kk = 0; kk < 64; kk += 32) {
      const int kbyte = (kk + lq * 8) * 2;
      f16x8 af[4], bf[2];
#pragma unroll
      for (int mt = 0; mt < 4; ++mt) {
        const int row = wm * 64 + mt * 16 + lrow;
        af[mt] = *reinterpret_cast<const f16x8*>(&As[row * 128 + (kbyte ^ ((row & 7) << 4))]);
      }
#pragma unroll
      for (int nt = 0; nt < 2; ++nt) {
        const int row = wn * 32 + nt * 16 + lrow;
        bf[nt] = *reinterpret_cast<const f16x8*>(&Bs[row * 128 + (kbyte ^ ((row & 7) << 4))]);
      }
#pragma unroll
      for (int mt = 0; mt < 4; ++mt)
#pragma unroll
        for (int nt = 0; nt < 2; ++nt)
          acc[mt][nt] = __builtin_amdgcn_mfma_f32_16x16x32_f16(af[mt], bf[nt], acc[mt][nt], 0, 0, 0);
    }
    __syncthreads();
  }

#pragma unroll
  for (int nt = 0; nt < 2; ++nt) {
    const int n = n0 + wn * 32 + nt * 16 + lrow;
    float bias = (MODE == 0) ? (b0[n] + b1[n]) : b0[n];
#pragma unroll
    for (int mt = 0; mt < 4; ++mt) {
#pragma unroll
      for (int r = 0; r < 4; ++r) {
        const int m = m0 + wm * 64 + mt * 16 + lq * 4 + r;
        float val = acc[mt][nt][r] + bias;
        if (MODE == 1) val = fmaxf(val, 0.f);
        if (MODE == 2) val = fast_tanh(val);
        C[(size_t)m * N + n] = val;
      }
    }
  }
}

// ---------------------------------------------------------------------------
// Fused fw+bw input-projection GEMM, f16 output. blockIdx.z selects the
// direction's weights/biases/output. C_h = A @ W^T + bih + bhh (as __half).
// Same tile structure as gemm_mfma.
// ---------------------------------------------------------------------------
__global__ __launch_bounds__(256) void gemm_proj_h(
    const float* __restrict__ A,
    const float* __restrict__ W0, const float* __restrict__ W1,
    const float* __restrict__ bi0, const float* __restrict__ bh0,
    const float* __restrict__ bi1, const float* __restrict__ bh1,
    __half* __restrict__ C0, __half* __restrict__ C1, int M, int N, int K) {
  const float* __restrict__ W  = blockIdx.z ? W1 : W0;
  const float* __restrict__ b0 = blockIdx.z ? bi1 : bi0;
  const float* __restrict__ b1 = blockIdx.z ? bh1 : bh0;
  __half* __restrict__ C = blockIdx.z ? C1 : C0;

  __shared__ __align__(16) unsigned char As[128 * 128];
  __shared__ __align__(16) unsigned char Bs[64 * 128];
  const int tid = threadIdx.x;
  const int wave = tid >> 6, l = tid & 63;
  const int wm = wave >> 1, wn = wave & 1;
  const int m0 = blockIdx.x * 128, n0 = blockIdx.y * 64;
  const int lrow = l & 15, lq = l >> 4;

  f32x4 acc[4][2] = {};
  const int arow = tid >> 1, akc = (tid & 1) * 32;
  const int brow = tid >> 2, bkc = (tid & 3) * 16;

  for (int k0 = 0; k0 < K; k0 += 64) {
    {
      const float* src = A + (size_t)(m0 + arow) * K + k0 + akc;
#pragma unroll
      for (int u = 0; u < 4; ++u) {
        float4 v0 = *reinterpret_cast<const float4*>(src + u * 8);
        float4 v1 = *reinterpret_cast<const float4*>(src + u * 8 + 4);
        f16x8 h;
        h[0] = (_Float16)v0.x; h[1] = (_Float16)v0.y;
        h[2] = (_Float16)v0.z; h[3] = (_Float16)v0.w;
        h[4] = (_Float16)v1.x; h[5] = (_Float16)v1.y;
        h[6] = (_Float16)v1.z; h[7] = (_Float16)v1.w;
        const int kbyte = (akc + u * 8) * 2;
        *reinterpret_cast<f16x8*>(&As[arow * 128 + (kbyte ^ ((arow & 7) << 4))]) = h;
      }
    }
    {
      const float* src = W + (size_t)(n0 + brow) * K + k0 + bkc;
#pragma unroll
      for (int u = 0; u < 2; ++u) {
        float4 v0 = *reinterpret_cast<const float4*>(src + u * 8);
        float4 v1 = *reinterpret_cast<const float4*>(src + u * 8 + 4);
        f16x8 h;
        h[0] = (_Float16)v0.x; h[1] = (_Float16)v0.y;
        h[2] = (_Float16)v0.z; h[3] = (_Float16)v0.w;
        h[4] = (_Float16)v1.x; h[5] = (_Float16)v1.y;
        h[6] = (_Float16)v1.z; h[7] = (_Float16)v1.w;
        const int kbyte = (bkc + u * 8) * 2;
        *reinterpret_cast<f16x8*>(&Bs[brow * 128 + (kbyte ^ ((brow & 7) << 4))]) = h;
      }
    }
    __syncthreads();
#pragma unroll
    for (int kk = 0; kk < 64; kk += 32) {
      const int kbyte = (kk + lq * 8) * 2;
      f16x8 af[4], bf[2];
#pragma unroll
      for (int mt = 0; mt < 4; ++mt) {
        const int row = wm * 64 + mt * 16 + lrow;
        af[mt] = *reinterpret_cast<const f16x8*>(&As[row * 128 + (kbyte ^ ((row & 7) << 4))]);
      }
#pragma unroll
      for (int nt = 0; nt < 2; ++nt) {
        const int row = wn * 32 + nt * 16 + lrow;
        bf[nt] = *reinterpret_cast<const f16x8*>(&Bs[row * 128 + (kbyte ^ ((row & 7) << 4))]);
      }
#pragma unroll
      for (int mt = 0; mt < 4; ++mt)
#pragma unroll
        for (int nt = 0; nt < 2; ++nt)
          acc[mt][nt] = __builtin_amdgcn_mfma_f32_16x16x32_f16(af[mt], bf[nt], acc[mt][nt], 0, 0, 0);
    }
    __syncthreads();
  }

#pragma unroll
  for (int nt = 0; nt < 2; ++nt) {
    const int n = n0 + wn * 32 + nt * 16 + lrow;
    const float bias = b0[n] + b1[n];
#pragma unroll
    for (int mt = 0; mt < 4; ++mt) {
#pragma unroll
      for (int r = 0; r < 4; ++r) {
        const int m = m0 + wm * 64 + mt * 16 + lq * 4 + r;
        C[(size_t)m * N + n] = __float2half_rn(acc[mt][nt][r] + bias);
      }
    }
  }
}

// ---------------------------------------------------------------------------
// LSTM recurrence, v6: 8-way k-split. One 512-thread block per (batch,dir).
// Lane (g6 = tid>>3, e = tid&7): units {2g6, 2g6+1} x 4 gates over
// k in [16e, 16e+16): 64 dot2/lane, but only 32B of LDS h per lane
// (halved broadcast-return vs v5). Reduce over the 8 e-lanes with 3 DPP
// stages (xor1, xor2, row_half_mirror). Each lane activates ONE gate-row
// (e-map chosen so half_mirror + quad_perm gather i,f,g,o to lanes e=0,1
// which own c/h of units 2g6+e). xg is f16. Raw lgkmcnt-only barrier;
// xg prefetch rotation xva/xvb (in flight across barriers).
// ---------------------------------------------------------------------------
__global__ __launch_bounds__(512, 1) void lstm_seq6(
    const __half* __restrict__ xg_f, const __half* __restrict__ xg_b,
    const float* __restrict__ Whh_f, const float* __restrict__ Whh_b,
    float* __restrict__ out) {
  const int b = blockIdx.x;
  const int dir = blockIdx.y;
  const int tid = threadIdx.x;
  const int g6 = tid >> 3;  // unit-pair group 0..63
  const int e = tid & 7;    // k-eighth
  const __half* __restrict__ xg = dir ? xg_b : xg_f;
  const float* __restrict__ Whh = dir ? Whh_b : Whh_f;

  __shared__ unsigned int hbuf[2][64];  // h as f16 pairs, double-buffered

  // weights: w[g][u][kk] = f16x2 of row (g*128 + 2g6+u), k = 16e + 2kk (+1)
  unsigned int w[4][2][8];
#pragma unroll
  for (int g = 0; g < 4; ++g)
#pragma unroll
    for (int u = 0; u < 2; ++u) {
      const float4* wr = reinterpret_cast<const float4*>(
          Whh + (size_t)(g * 128 + 2 * g6 + u) * 128 + e * 16);
#pragma unroll
      for (int q = 0; q < 4; ++q) {
        float4 v = wr[q];
        __half2 p0 = __floats2half2_rn(v.x, v.y);
        __half2 p1 = __floats2half2_rn(v.z, v.w);
        w[g][u][2 * q]     = __builtin_bit_cast(unsigned int, p0);
        w[g][u][2 * q + 1] = __builtin_bit_cast(unsigned int, p1);
      }
    }

  // e -> (gate, unit-within-pair): 0:(i,0) 1:(i,1) 2:(f,0) 3:(f,1)
  //                                4:(o,1) 5:(o,0) 6:(g,1) 7:(g,0)
  const int gate_e = (e < 4) ? (e >> 1) : (5 - (e >> 1));
  const int u_e = (e < 4) ? (e & 1) : ((e & 1) ^ 1);
  const int xidx = gate_e * 128 + 2 * g6 + u_e;

  if (tid < 128) reinterpret_cast<unsigned int*>(hbuf)[tid] = 0u;
  float c = 0.f;
  __syncthreads();

  const int tt0 = dir ? 511 : 0;
  const int stp = dir ? -1 : 1;
  const size_t base = (size_t)b * 512 * 512;

  unsigned short xva = __builtin_bit_cast(unsigned short, xg[base + (size_t)tt0 * 512 + xidx]);
  unsigned short xvb = __builtin_bit_cast(unsigned short, xg[base + (size_t)(tt0 + stp) * 512 + xidx]);

  auto step = [&](int t, unsigned int* rbuf, unsigned int* wbuf, unsigned short& xcur)
      __attribute__((always_inline)) {
    const int tt = tt0 + stp * t;

    // my 32B h slice: 2 x ds_read_b128
    const uint4* hc = reinterpret_cast<const uint4*>(&rbuf[e * 8]);
    uint4 q0 = hc[0], q1 = hc[1];
    unsigned int ha[8];
    ha[0] = q0.x; ha[1] = q0.y; ha[2] = q0.z; ha[3] = q0.w;
    ha[4] = q1.x; ha[5] = q1.y; ha[6] = q1.z; ha[7] = q1.w;

    float acc[4][2] = {};
#pragma unroll
    for (int kk = 0; kk < 8; ++kk) {
#pragma unroll
      for (int g = 0; g < 4; ++g) {
#pragma unroll
        for (int u = 0; u < 2; ++u)
          acc[g][u] = fdot2u(w[g][u][kk], ha[kk], acc[g][u]);
      }
    }

    // reduce over the 8 e-lanes: xor1, xor2, half-mirror (e <-> 7-e)
#pragma unroll
    for (int g = 0; g < 4; ++g)
#pragma unroll
      for (int u = 0; u < 2; ++u) {
        float a = acc[g][u];
        a = dpp_add<0xB1>(a);   // quad_perm [1,0,3,2]  (e^1)
        a = dpp_add<0x4E>(a);   // quad_perm [2,3,0,1]  (e^2)
        a = dpp_add<0x141>(a);  // row_half_mirror      (7-e)
        acc[g][u] = a;
      }

    // lane e takes its row per the e-map
    float a = acc[0][0];
    a = (e == 1) ? acc[0][1] : a;
    a = (e == 2) ? acc[1][0] : a;
    a = (e == 3) ? acc[1][1] : a;
    a = (e == 4) ? acc[3][1] : a;
    a = (e == 5) ? acc[3][0] : a;
    a = (e == 6) ? acc[2][1] : a;
    a = (e == 7) ? acc[2][0] : a;
    a += (float)__builtin_bit_cast(_Float16, xcur);

    // prefetch xg for t+2 (stays in flight across raw barriers)
    {
      const int t2 = t + 2;
      const int tt2 = (t2 < 512) ? (tt0 + stp * t2) : tt0;
      xcur = __builtin_bit_cast(unsigned short, xg[base + (size_t)tt2 * 512 + xidx]);
    }

    const float xs = (e >= 6) ? 2.f * a : a;
    const float y = fast_sigmoid(xs);
    const float act = (e >= 6) ? 2.f * y - 1.f : y;

    // gather: lanes 0,1 get (i,f,g,o) of units 2g6, 2g6+1
    const float m = dpp_mov<0x141>(act);   // lane e <- act[7-e]  (g rows)
    const float fq = dpp_mov<0x4E>(act);   // lane 0<-2, 1<-3     (f rows)
    const float oq = dpp_mov<0x4E>(m);     // lane 0<-m[2], 1<-m[3] (o rows)

    c = fq * c + act * m;                  // f*c + i*g (valid on lanes 0,1)
    const float h = oq * (2.f * fast_sigmoid(2.f * c) - 1.f);

    if (e < 2) {
      unsigned short us = __builtin_bit_cast(unsigned short, (_Float16)h);
      reinterpret_cast<unsigned short*>(wbuf)[2 * g6 + e] = us;
      out[((size_t)b * 512 + tt) * 256 + dir * 128 + 2 * g6 + e] = h;
    }

    asm volatile("s_waitcnt lgkmcnt(0)" ::: "memory");
    __builtin_amdgcn_s_barrier();
    asm volatile("" ::: "memory");
  };

  for (int it = 0; it < 256; ++it) {
    step(2 * it,     hbuf[0], hbuf[1], xva);
    step(2 * it + 1, hbuf[1], hbuf[0], xvb);
  }
}

// ---------------------------------------------------------------------------
// Launcher
// ---------------------------------------------------------------------------
extern "C" void kernel_launch(void* const* d_in, const int* in_sizes, int n_in,
                              void* d_out, int out_size, void* d_ws, size_t ws_size,
                              hipStream_t stream) {
  (void)in_sizes; (void)n_in; (void)out_size; (void)ws_size;

  const float* x     = (const float*)d_in[0];
  const float* Wih00 = (const float*)d_in[1];
  const float* Whh00 = (const float*)d_in[2];
  const float* bih00 = (const float*)d_in[3];
  const float* bhh00 = (const float*)d_in[4];
  const float* Wih01 = (const float*)d_in[5];
  const float* Whh01 = (const float*)d_in[6];
  const float* bih01 = (const float*)d_in[7];
  const float* bhh01 = (const float*)d_in[8];
  const float* Wih10 = (const float*)d_in[9];
  const float* Whh10 = (const float*)d_in[10];
  const float* bih10 = (const float*)d_in[11];
  const float* bhh10 = (const float*)d_in[12];
  const float* Wih11 = (const float*)d_in[13];
  const float* Whh11 = (const float*)d_in[14];
  const float* bih11 = (const float*)d_in[15];
  const float* bhh11 = (const float*)d_in[16];
  const float* W1 = (const float*)d_in[17];
  const float* b1 = (const float*)d_in[18];
  const float* W2 = (const float*)d_in[19];
  const float* b2 = (const float*)d_in[20];
  float* out = (float*)d_out;

  char* ws = (char*)d_ws;
  __half* xgh_f = (__half*)ws;                          // 32 MB [B,T,512] f16
  __half* xgh_b = (__half*)(ws + ((size_t)32 << 20));   // 32 MB
  float*  buf   = (float*)(ws + ((size_t)64 << 20));    // 32 MB [B,T,256] f32
  float*  tmp   = (float*)(ws + ((size_t)96 << 20));    // 32 MB head intermediate

  const int M = 64 * 512;  // 32768 rows

  // ---- layer 0 ----
  gemm_proj_h<<<dim3(M / 128, 8, 2), 256, 0, stream>>>(
      x, Wih00, Wih01, bih00, bhh00, bih01, bhh01, xgh_f, xgh_b, M, 512, 64);
  lstm_seq6<<<dim3(64, 2), 512, 0, stream>>>(xgh_f, xgh_b, Whh00, Whh01, buf);

  // ---- layer 1 ----
  gemm_proj_h<<<dim3(M / 128, 8, 2), 256, 0, stream>>>(
      buf, Wih10, Wih11, bih10, bhh10, bih11, bhh11, xgh_f, xgh_b, M, 512, 256);
  lstm_seq6<<<dim3(64, 2), 512, 0, stream>>>(xgh_f, xgh_b, Whh10, Whh11, buf);

  // ---- head ----
  gemm_mfma<1><<<dim3(M / 128, 4), 256, 0, stream>>>(
      buf, W1, b1, nullptr, tmp, M, 256, 256);
  gemm_mfma<2><<<dim3(M / 128, 1), 256, 0, stream>>>(
      tmp, W2, b2, nullptr, out, M, 64, 256);
}